// Round 6
// baseline (575.441 us; speedup 1.0000x reference)
//
#include <hip/hip_runtime.h>
#include <stdint.h>

// Problem constants (B, T, V, E, U)
constexpr int NB = 1024;
constexpr int NT = 80;
constexpr int NV = 50000;
constexpr int NE = 512;
constexpr int NU = 512;

typedef __attribute__((ext_vector_type(8))) __bf16 bf16x8;
typedef __attribute__((ext_vector_type(4))) float f32x4;
typedef __attribute__((ext_vector_type(4))) uint16_t u16x4;
typedef __attribute__((ext_vector_type(4))) float float4v;
typedef __attribute__((ext_vector_type(4))) uint32_t u32x4;

__device__ __forceinline__ uint16_t f2bf(float f) {
  uint32_t u = __builtin_bit_cast(uint32_t, f);
  u += 0x7FFFu + ((u >> 16) & 1u);   // round-to-nearest-even
  return (uint16_t)(u >> 16);
}
__device__ __forceinline__ float bf2f(uint16_t h) {
  uint32_t u = ((uint32_t)h) << 16;
  return __builtin_bit_cast(float, u);
}
__device__ __forceinline__ float tanh_fast(float x) {
  float e = __expf(2.0f * x);
  return 1.0f - 2.0f / (e + 1.0f);
}

// ---------------- prep kernels (unchanged) ----------------

__global__ __launch_bounds__(256) void emb_to_bf16(const float* __restrict__ in,
                                                   uint16_t* __restrict__ out) {
  int i = blockIdx.x * 256 + threadIdx.x;           // 6,400,000 float4s
  float4v v = ((const float4v*)in)[i];
  u16x4 o;
  o.x = f2bf(v.x); o.y = f2bf(v.y); o.z = f2bf(v.z); o.w = f2bf(v.w);
  ((u16x4*)out)[i] = o;
}

// Pack a [K=512][N=512] fp32 weight into MFMA-B-fragment order:
// pack[nt][ks][lane][j] = bf16( W[ks*32 + (lane>>4)*8 + j][nt*16 + (lane&15)] )
__global__ __launch_bounds__(256) void pack_w(const float* __restrict__ w,
                                              uint16_t* __restrict__ out) {
  int idx = blockIdx.x * 256 + threadIdx.x;  // 0..32767 = 32 nt * 16 ks * 64 lanes
  int lane = idx & 63;
  int ks = (idx >> 6) & 15;
  int nt = idx >> 10;
  int n  = nt * 16 + (lane & 15);
  int k0 = ks * 32 + (lane >> 4) * 8;
  uint16_t v[8];
#pragma unroll
  for (int j = 0; j < 8; j++) v[j] = f2bf(w[(size_t)(k0 + j) * NU + n]);
  u16x4* o = (u16x4*)(out + (size_t)idx * 8);
  o[0] = (u16x4){v[0], v[1], v[2], v[3]};
  o[1] = (u16x4){v[4], v[5], v[6], v[7]};
}

// ---------------- projection GEMM (unchanged) -------
__global__ __launch_bounds__(256, 2) void proj_gemm(const int* __restrict__ tokens,
                                                    const uint16_t* __restrict__ embb,
                                                    const uint16_t* __restrict__ kpack,
                                                    const float* __restrict__ bias,
                                                    uint16_t* __restrict__ xkp) {
  int wave = threadIdx.x >> 6;
  int lane = threadIdx.x & 63;
  int ln15 = lane & 15;
  int quad = lane >> 4;
  int m0 = blockIdx.x * 64;      // 1280 blocks: 80 t x 16 b-groups
  int t = m0 >> 10;
  int b0 = m0 & 1023;

  int tok[4];
#pragma unroll
  for (int mt = 0; mt < 4; mt++)
    tok[mt] = tokens[(size_t)(b0 + mt * 16 + ln15) * NT + t];

  float bv[8];
#pragma unroll
  for (int nt = 0; nt < 8; nt++) bv[nt] = bias[wave * 128 + nt * 16 + ln15];

  f32x4 acc[4][8];
#pragma unroll
  for (int mt = 0; mt < 4; mt++)
#pragma unroll
    for (int nt = 0; nt < 8; nt++) acc[mt][nt] = (f32x4){0.f, 0.f, 0.f, 0.f};

  bf16x8 aC[4], aN[4];
#pragma unroll
  for (int mt = 0; mt < 4; mt++) {
    aC[mt] = *(const bf16x8*)(embb + (size_t)tok[mt] * NE + 0 * 32 + quad * 8);
    aN[mt] = *(const bf16x8*)(embb + (size_t)tok[mt] * NE + 1 * 32 + quad * 8);
  }

#pragma unroll 1
  for (int ks = 0; ks < 16; ks++) {
    bf16x8 aF[4];
    int ksn = (ks + 2) & 15;   // wraps harmlessly for ks=14,15
#pragma unroll
    for (int mt = 0; mt < 4; mt++)
      aF[mt] = *(const bf16x8*)(embb + (size_t)tok[mt] * NE + ksn * 32 + quad * 8);
#pragma unroll
    for (int nt = 0; nt < 8; nt++) {
      int ntg = wave * 8 + nt;
      bf16x8 bfr = *(const bf16x8*)(kpack + (((size_t)ntg * 16 + ks) * 64 + lane) * 8);
#pragma unroll
      for (int mt = 0; mt < 4; mt++)
        acc[mt][nt] = __builtin_amdgcn_mfma_f32_16x16x32_bf16(aC[mt], bfr, acc[mt][nt], 0, 0, 0);
    }
#pragma unroll
    for (int mt = 0; mt < 4; mt++) { aC[mt] = aN[mt]; aN[mt] = aF[mt]; }
  }

  // epilogue: C-fragment-order tiles, coalesced 8B/lane stores
#pragma unroll
  for (int mt = 0; mt < 4; mt++) {
    int g = (b0 >> 4) + mt;
#pragma unroll
    for (int nt = 0; nt < 8; nt++) {
      int ntg = wave * 8 + nt;
      size_t tile = ((size_t)t * 64 + g) * 32 + ntg;
      u16x4 o;
      o.x = f2bf(acc[mt][nt][0] + bv[nt]);
      o.y = f2bf(acc[mt][nt][1] + bv[nt]);
      o.z = f2bf(acc[mt][nt][2] + bv[nt]);
      o.w = f2bf(acc[mt][nt][3] + bv[nt]);
      *(u16x4*)(xkp + tile * 256 + (size_t)lane * 4) = o;
    }
  }
}

// ---------------- recurrence: 4-wave blocks, TRUE full-R persistence ------
// 64 blocks x 256 threads (4 waves, 1 wave/SIMD, 1 block/CU). Block g owns
// rows g*16..+15, all 512 cols. Wave w owns n-tiles w*8..+7 (128 cols).
//
// Round-5 post-mortem: at 8-wave blocks the per-wave register budget is 256
// TOTAL across the unified VGPR+AGPR file (2 waves/SIMD; per-SIMD file =
// 512 slots, m69). bP(192)+live(~128) could never be resident -> allocator
// re-fetched R from L2 every step (invisible in FETCH: rpack is L2-hot).
// That's why rounds 2/4/5 all sit at 3.2-4.2us/step regardless of stream
// structure. Fix: 4-wave blocks -> 1 wave/SIMD -> ~512 regs/wave budget.
//   * ks 0..11 -> registers: bP[12][8] = 384 regs/wave (demand ~460 < 512,
//     no scratch spill expected per m08; no class-forcing asm pins)
//   * ks 12..15 -> bL in LDS (128 KB, all 32 nt, lane-linear b128)
// Per-step global traffic: ONLY the 16KB xk read (issued at step top,
// consumed at tanh). Per wave per step: 16 A-reads + 32 bq reads + 128
// MFMA + 32-elem tanh + 32 u16 repack writes; 2 barriers.
// h-tile: 16 KB LDS, A-frag layout, XOR-swizzled slot (verified: conflicts
// 6.5M -> 12K). Counters adjudicate: FETCH>>43MB => remat; WRITE>>0 =>
// spill; VGPR_Count ~256 => residency achieved.
__global__ __launch_bounds__(256, 1)
void rnn_rec(const uint16_t* __restrict__ xkp,
             const uint16_t* __restrict__ rpack,
             const float* __restrict__ fcw,
             const float* __restrict__ fcb,
             float* __restrict__ out) {
  __shared__ uint16_t hS[8192];              // 16 KB h-tile (single buffer)
  __shared__ uint16_t bL[4 * 32 * 64 * 8];   // 128 KB: B-frags ks 12..15, all nt

  const int g = blockIdx.x;
  const int wave = threadIdx.x >> 6, lane = threadIdx.x & 63;
  const int ln15 = lane & 15, quad = lane >> 4;
  const int ntg0 = wave * 8;                    // first owned n-tile (of 32)
  const int aswz = quad ^ ((ln15 >> 1) & 3);    // swizzled 16B-slot for A-reads

  // persistent B-frags ks 0..11 (384 regs/wave across unified VGPR+AGPR)
  bf16x8 bP[12][8];
#pragma unroll
  for (int ks = 0; ks < 12; ks++)
#pragma unroll
    for (int n = 0; n < 8; n++)
      bP[ks][n] = *(const bf16x8*)(rpack + (((size_t)(ntg0 + n) * 16 + ks) * 64 + lane) * 8);

  // fill bL: 8192 frags (4 ksl x 32 nt x 64 lanes), 16 B each (ks 12..15)
#pragma unroll
  for (int i = 0; i < 32; i++) {
    int f = i * 256 + threadIdx.x;
    int l = f & 63, nt = (f >> 6) & 31, ksl = f >> 11;
    *(u32x4*)(bL + (size_t)f * 8) =
        *(const u32x4*)(rpack + (((size_t)nt * 16 + 12 + ksl) * 64 + l) * 8);
  }

  // h(0) = 0
  {
    u32x4 z = (u32x4){0u, 0u, 0u, 0u};
#pragma unroll
    for (int i = 0; i < 4; i++) ((u32x4*)hS)[i * 256 + threadIdx.x] = z;
  }

  // xk pointer for step t (advanced +1MB/step); nt offsets are imm 512B
  const uint16_t* xp = xkp + ((size_t)g * 32 + ntg0) * 256 + (size_t)lane * 4;

  __syncthreads();

#pragma unroll 1
  for (int t = 0; t < NT; ++t) {
    // xk(t): consumed at the tanh after the full MFMA phase -> hidden
    u16x4 xc[8];
#pragma unroll
    for (int n = 0; n < 8; n++)
      xc[n] = *(const u16x4*)(xp + n * 256);

    f32x4 acc[8];
#pragma unroll
    for (int n = 0; n < 8; n++) acc[n] = (f32x4){0.f, 0.f, 0.f, 0.f};

    // phase 1: ks 0..11, B from registers (8 independent acc chains)
#pragma unroll
    for (int ks = 0; ks < 12; ks++) {
      bf16x8 a = *(const bf16x8*)(hS + (size_t)ks * 512 + ln15 * 32 + aswz * 8);
#pragma unroll
      for (int n = 0; n < 8; n++)
        acc[n] = __builtin_amdgcn_mfma_f32_16x16x32_bf16(a, bP[ks][n], acc[n], 0, 0, 0);
    }

    // phase 2: ks 12..15, B from bL (LDS, conflict-free lane-linear b128)
#pragma unroll
    for (int ksl = 0; ksl < 4; ksl++) {
      bf16x8 a = *(const bf16x8*)(hS + (size_t)(12 + ksl) * 512 + ln15 * 32 + aswz * 8);
#pragma unroll
      for (int n = 0; n < 8; n++) {
        bf16x8 bq = *(const bf16x8*)(bL + (((size_t)ksl * 32 + ntg0 + n) * 64 + lane) * 8);
        acc[n] = __builtin_amdgcn_mfma_f32_16x16x32_bf16(a, bq, acc[n], 0, 0, 0);
      }
    }

    // tanh (32 values)
    uint16_t hv[8][4];
#pragma unroll
    for (int n = 0; n < 8; n++)
#pragma unroll
      for (int r = 0; r < 4; r++)
        hv[n][r] = f2bf(tanh_fast(acc[n][r] + bf2f(xc[n][r])));

    xp += (size_t)64 * 32 * 256;   // advance to step t+1 (+1 MB)

    __syncthreads();   // all hS reads of step t done

    // repack own 128 cols into hS (swizzled scatter; wave-local regions)
#pragma unroll
    for (int n = 0; n < 8; n++) {
      int col = wave * 128 + n * 16 + ln15;
      int ksR = col >> 5;
      int qw = (col >> 3) & 3;
      int j = col & 7;
#pragma unroll
      for (int r = 0; r < 4; r++) {
        int row = quad * 4 + r;
        hS[(size_t)ksR * 512 + row * 32 + ((qw ^ ((row >> 1) & 3)) << 3) + j] = hv[n][r];
      }
    }
    __syncthreads();   // h(t+1) complete
  }

  // final FC + sigmoid: each wave does 4 rows (4 waves x 4 = 16)
  {
#pragma unroll
    for (int rr = 0; rr < 4; rr++) {
      int row = wave * 4 + rr;
      // cols lane*8..+7: ks = lane>>2, logical qw = lane&3 -> swizzled slot
      int slot = (lane & 3) ^ ((row >> 1) & 3);
      const uint16_t* hr = hS + (size_t)(lane >> 2) * 512 + row * 32 + slot * 8;
      float p = 0.f;
#pragma unroll
      for (int j = 0; j < 8; j++) p += bf2f(hr[j]) * fcw[lane * 8 + j];
#pragma unroll
      for (int off = 32; off; off >>= 1) p += __shfl_down(p, off);
      if (lane == 0) {
        float logit = p + fcb[0];
        out[g * 16 + row] = 1.0f / (1.0f + __expf(-logit));
      }
    }
  }
}

// ---------------- launcher ----------------
extern "C" void kernel_launch(void* const* d_in, const int* in_sizes, int n_in,
                              void* d_out, int out_size, void* d_ws, size_t ws_size,
                              hipStream_t stream) {
  const int* tokens   = (const int*)d_in[0];
  const float* emb    = (const float*)d_in[1];
  const float* kernel_w = (const float*)d_in[2];
  const float* rec_w  = (const float*)d_in[3];
  const float* bias   = (const float*)d_in[4];
  const float* fcw    = (const float*)d_in[5];
  const float* fcb    = (const float*)d_in[6];
  float* out = (float*)d_out;

  // workspace: emb_bf16 51.2MB | kpack 0.5MB | rpack 0.5MB | xkp 83.9MB
  uint16_t* embb  = (uint16_t*)d_ws;
  uint16_t* kpack = embb + (size_t)NV * NE;
  uint16_t* rpack = kpack + (size_t)NE * NU;
  uint16_t* xkp   = rpack + (size_t)NU * NU;

  hipLaunchKernelGGL(emb_to_bf16, dim3(25000), dim3(256), 0, stream, emb, embb);
  hipLaunchKernelGGL(pack_w, dim3(128), dim3(256), 0, stream, kernel_w, kpack);
  hipLaunchKernelGGL(pack_w, dim3(128), dim3(256), 0, stream, rec_w, rpack);
  hipLaunchKernelGGL(proj_gemm, dim3(1280), dim3(256), 0, stream, tokens, embb, kpack, bias, xkp);
  hipLaunchKernelGGL(rnn_rec, dim3(64), dim3(256), 0, stream, xkp, rpack, fcw, fcb, out);
}

// Round 8
// 474.214 us; speedup vs baseline: 1.2135x; 1.2135x over previous
//
#include <hip/hip_runtime.h>
#include <stdint.h>

// Problem constants (B, T, V, E, U)
constexpr int NB = 1024;
constexpr int NT = 80;
constexpr int NV = 50000;
constexpr int NE = 512;
constexpr int NU = 512;

typedef __attribute__((ext_vector_type(8))) __bf16 bf16x8;
typedef __attribute__((ext_vector_type(4))) float f32x4;
typedef __attribute__((ext_vector_type(4))) uint16_t u16x4;
typedef __attribute__((ext_vector_type(4))) float float4v;
typedef __attribute__((ext_vector_type(4))) uint32_t u32x4;

__device__ __forceinline__ uint16_t f2bf(float f) {
  uint32_t u = __builtin_bit_cast(uint32_t, f);
  u += 0x7FFFu + ((u >> 16) & 1u);   // round-to-nearest-even
  return (uint16_t)(u >> 16);
}
__device__ __forceinline__ float bf2f(uint16_t h) {
  uint32_t u = ((uint32_t)h) << 16;
  return __builtin_bit_cast(float, u);
}
__device__ __forceinline__ float tanh_fast(float x) {
  float e = __expf(2.0f * x);
  return 1.0f - 2.0f / (e + 1.0f);
}

// LLC-coherent (device-scope) 16B load/store: sc0 sc1 bypass L1+L2 -> data
// lives at the Infinity Cache coherence point; correct for any XCD placement.
__device__ __forceinline__ void store16_cc(uint16_t* p, u32x4 v) {
  asm volatile("global_store_dwordx4 %0, %1, off sc0 sc1" :: "v"(p), "v"(v) : "memory");
}
__device__ __forceinline__ u32x4 load16_cc(const uint16_t* p) {
  u32x4 r;
  asm volatile("global_load_dwordx4 %0, %1, off sc0 sc1" : "=v"(r) : "v"(p) : "memory");
  return r;
}

// ---------------- prep kernels (unchanged) ----------------

__global__ __launch_bounds__(256) void emb_to_bf16(const float* __restrict__ in,
                                                   uint16_t* __restrict__ out) {
  int i = blockIdx.x * 256 + threadIdx.x;           // 6,400,000 float4s
  float4v v = ((const float4v*)in)[i];
  u16x4 o;
  o.x = f2bf(v.x); o.y = f2bf(v.y); o.z = f2bf(v.z); o.w = f2bf(v.w);
  ((u16x4*)out)[i] = o;
}

// Pack a [K=512][N=512] fp32 weight into MFMA-B-fragment order:
// pack[nt][ks][lane][j] = bf16( W[ks*32 + (lane>>4)*8 + j][nt*16 + (lane&15)] )
__global__ __launch_bounds__(256) void pack_w(const float* __restrict__ w,
                                              uint16_t* __restrict__ out) {
  int idx = blockIdx.x * 256 + threadIdx.x;  // 0..32767 = 32 nt * 16 ks * 64 lanes
  int lane = idx & 63;
  int ks = (idx >> 6) & 15;
  int nt = idx >> 10;
  int n  = nt * 16 + (lane & 15);
  int k0 = ks * 32 + (lane >> 4) * 8;
  uint16_t v[8];
#pragma unroll
  for (int j = 0; j < 8; j++) v[j] = f2bf(w[(size_t)(k0 + j) * NU + n]);
  u16x4* o = (u16x4*)(out + (size_t)idx * 8);
  o[0] = (u16x4){v[0], v[1], v[2], v[3]};
  o[1] = (u16x4){v[4], v[5], v[6], v[7]};
}

// ---------------- projection GEMM (unchanged) -------
__global__ __launch_bounds__(256, 2) void proj_gemm(const int* __restrict__ tokens,
                                                    const uint16_t* __restrict__ embb,
                                                    const uint16_t* __restrict__ kpack,
                                                    const float* __restrict__ bias,
                                                    uint16_t* __restrict__ xkp) {
  int wave = threadIdx.x >> 6;
  int lane = threadIdx.x & 63;
  int ln15 = lane & 15;
  int quad = lane >> 4;
  int m0 = blockIdx.x * 64;      // 1280 blocks: 80 t x 16 b-groups
  int t = m0 >> 10;
  int b0 = m0 & 1023;

  int tok[4];
#pragma unroll
  for (int mt = 0; mt < 4; mt++)
    tok[mt] = tokens[(size_t)(b0 + mt * 16 + ln15) * NT + t];

  float bv[8];
#pragma unroll
  for (int nt = 0; nt < 8; nt++) bv[nt] = bias[wave * 128 + nt * 16 + ln15];

  f32x4 acc[4][8];
#pragma unroll
  for (int mt = 0; mt < 4; mt++)
#pragma unroll
    for (int nt = 0; nt < 8; nt++) acc[mt][nt] = (f32x4){0.f, 0.f, 0.f, 0.f};

  bf16x8 aC[4], aN[4];
#pragma unroll
  for (int mt = 0; mt < 4; mt++) {
    aC[mt] = *(const bf16x8*)(embb + (size_t)tok[mt] * NE + 0 * 32 + quad * 8);
    aN[mt] = *(const bf16x8*)(embb + (size_t)tok[mt] * NE + 1 * 32 + quad * 8);
  }

#pragma unroll 1
  for (int ks = 0; ks < 16; ks++) {
    bf16x8 aF[4];
    int ksn = (ks + 2) & 15;   // wraps harmlessly for ks=14,15
#pragma unroll
    for (int mt = 0; mt < 4; mt++)
      aF[mt] = *(const bf16x8*)(embb + (size_t)tok[mt] * NE + ksn * 32 + quad * 8);
#pragma unroll
    for (int nt = 0; nt < 8; nt++) {
      int ntg = wave * 8 + nt;
      bf16x8 bfr = *(const bf16x8*)(kpack + (((size_t)ntg * 16 + ks) * 64 + lane) * 8);
#pragma unroll
      for (int mt = 0; mt < 4; mt++)
        acc[mt][nt] = __builtin_amdgcn_mfma_f32_16x16x32_bf16(aC[mt], bfr, acc[mt][nt], 0, 0, 0);
    }
#pragma unroll
    for (int mt = 0; mt < 4; mt++) { aC[mt] = aN[mt]; aN[mt] = aF[mt]; }
  }

  // epilogue: C-fragment-order tiles, coalesced 8B/lane stores
#pragma unroll
  for (int mt = 0; mt < 4; mt++) {
    int g = (b0 >> 4) + mt;
#pragma unroll
    for (int nt = 0; nt < 8; nt++) {
      int ntg = wave * 8 + nt;
      size_t tile = ((size_t)t * 64 + g) * 32 + ntg;
      u16x4 o;
      o.x = f2bf(acc[mt][nt][0] + bv[nt]);
      o.y = f2bf(acc[mt][nt][1] + bv[nt]);
      o.z = f2bf(acc[mt][nt][2] + bv[nt]);
      o.w = f2bf(acc[mt][nt][3] + bv[nt]);
      *(u16x4*)(xkp + tile * 256 + (size_t)lane * 4) = o;
    }
  }
}

// ---------------- recurrence: 2-way col split, per-wave exchange ---------
// EXACTLY 128 blocks x 512 threads (8 waves, 2 waves/SIMD -> TLP).
// Round-7 failure was the LAUNCHER: dim3(256) leftover launched 128 extra
// blocks (g=64..127) whose hx publishes (chunk 128..255) overwrote the
// flags array -> premature poll exits -> stale h reads (absmax 0.14).
// Algorithm unchanged; grid fixed to dim3(128).
//
// Block (g = bid>>1, s = bid&1) owns rows g*16..+15, cols s*256..+255.
// Wave w owns n-tiles ntg0 = s*16 + w*2 (+1) -> 32 cols.
// bP = 16ks x 2nt = 128 regs/wave: resident at the 256/wave cap WITH a
// co-resident wave per SIMD to hide latency (r2-r6 capacity trap avoided).
// Exchange: ONE partner; wave w's repacked 32 cols are exactly ks-region
// s*8+w (wave-local) -> per-wave publish (store->vmcnt->flag), per-wave
// poll+stage of partner region (1KB, 16B/lane), ONE __syncthreads per step
// (double-buffered 2x16KB h-tile). xk(t+1) prefetch hides under the poll.
// Protocol safety: flags monotonic per (chunk,wave); hx parity-2; producer
// reuses a parity buffer only after its own stage of the previous step
// succeeded, which implies the partner consumed it (r0/r1 induction).
__global__ __launch_bounds__(512, 1)
void rnn_rec(const uint16_t* __restrict__ xkp,
             const uint16_t* __restrict__ rpack,
             const float* __restrict__ fcw,
             const float* __restrict__ fcb,
             uint16_t* __restrict__ hx,    // [2][128][4096] u16 (8KB chunks)
             int* __restrict__ flags,      // [128][8] ints, stride 4 (16B)
             float* __restrict__ out) {
  __shared__ uint16_t hS[2 * 8192];        // two 16KB h-tiles (A-frag, swizzled)

  const int bid = blockIdx.x;
  const int g = bid >> 1, s = bid & 1;
  const int wave = threadIdx.x >> 6, lane = threadIdx.x & 63;
  const int ln15 = lane & 15, quad = lane >> 4;
  const int ntg0 = s * 16 + wave * 2;           // first of 2 owned n-tiles
  const int aswz = quad ^ ((ln15 >> 1) & 3);    // swizzled 16B-slot for A-reads

  // persistent B-frags: 16 ks x 2 nt = 128 regs/wave (cap 256 at 2/SIMD)
  bf16x8 bP[16][2];
#pragma unroll
  for (int ks = 0; ks < 16; ks++)
#pragma unroll
    for (int n = 0; n < 2; n++)
      bP[ks][n] = *(const bf16x8*)(rpack + (((size_t)(ntg0 + n) * 16 + ks) * 64 + lane) * 8);
#pragma unroll
  for (int ks = 0; ks < 16; ks++)
    asm volatile("" : "+v"(bP[ks][0]), "+v"(bP[ks][1]));   // one-time pin

  // h(0) = 0 in buffer 0 (buffer 1 is fully written at t=0)
  {
    u32x4 z = (u32x4){0u, 0u, 0u, 0u};
    ((u32x4*)hS)[threadIdx.x] = z;
    ((u32x4*)hS)[512 + threadIdx.x] = z;
  }

  const int regionOwn = s * 8 + wave;           // own ks-region in h-tile
  const int regionPar = (1 - s) * 8 + wave;     // partner's ks-region
  const int chunkOwn = g * 2 + s;
  const int chunkPar = g * 2 + (1 - s);
  int* flagOwn = flags + (chunkOwn * 8 + wave) * 4;
  const int* flagPar = flags + (chunkPar * 8 + wave) * 4;

  // xk pointer for step t; two owned tiles at imm offsets 0 / 512B
  const uint16_t* xp = xkp + ((size_t)g * 32 + ntg0) * 256 + (size_t)lane * 4;
  u16x4 xc0 = *(const u16x4*)(xp);
  u16x4 xc1 = *(const u16x4*)(xp + 256);

  __syncthreads();

#pragma unroll 1
  for (int t = 0; t < NT; ++t) {
    const uint16_t* hR = hS + (t & 1) * 8192;
    uint16_t* hW = hS + ((t & 1) ^ 1) * 8192;

    // M: 16 ks, A from hR (all local), B from registers (2 acc chains)
    f32x4 acc0 = (f32x4){0.f, 0.f, 0.f, 0.f};
    f32x4 acc1 = (f32x4){0.f, 0.f, 0.f, 0.f};
#pragma unroll
    for (int ks = 0; ks < 16; ks++) {
      bf16x8 a = *(const bf16x8*)(hR + (size_t)ks * 512 + ln15 * 32 + aswz * 8);
      acc0 = __builtin_amdgcn_mfma_f32_16x16x32_bf16(a, bP[ks][0], acc0, 0, 0, 0);
      acc1 = __builtin_amdgcn_mfma_f32_16x16x32_bf16(a, bP[ks][1], acc1, 0, 0, 0);
    }

    // tanh (8 values/lane)
    uint16_t hv0[4], hv1[4];
#pragma unroll
    for (int r = 0; r < 4; r++) {
      hv0[r] = f2bf(tanh_fast(acc0[r] + bf2f(xc0[r])));
      hv1[r] = f2bf(tanh_fast(acc1[r] + bf2f(xc1[r])));
    }

    // repack own 32 cols into hW region regionOwn (wave-local), swizzled
#pragma unroll
    for (int n = 0; n < 2; n++) {
      const uint16_t* hv = (n == 0) ? hv0 : hv1;
      int qw = n * 2 + (ln15 >> 3);
      int j = ln15 & 7;
#pragma unroll
      for (int r = 0; r < 4; r++) {
        int row = quad * 4 + r;
        hW[(size_t)regionOwn * 512 + row * 32 + ((qw ^ ((row >> 1) & 3)) << 3) + j] = hv[r];
      }
    }
    asm volatile("s_waitcnt lgkmcnt(0)" ::: "memory");   // own ds_writes done

    // publish own 1KB region (per-wave, no barrier): store -> vmcnt -> flag
    {
      u32x4 d = *(const u32x4*)(hW + (size_t)regionOwn * 512 + (size_t)lane * 8);
      uint16_t* dst = hx + ((size_t)((t + 1) & 1) * 128 + chunkOwn) * 4096 +
                      (size_t)wave * 512 + (size_t)lane * 8;
      store16_cc(dst, d);
      asm volatile("s_waitcnt vmcnt(0)" ::: "memory");
      if (lane == 0)
        __hip_atomic_store(flagOwn, t + 1, __ATOMIC_RELAXED, __HIP_MEMORY_SCOPE_AGENT);
    }

    // prefetch xk(t+1): its HBM latency hides under the poll window
    const uint16_t* xq = (t + 1 < NT) ? xp + (size_t)64 * 32 * 256 : xp;
    u16x4 xn0 = *(const u16x4*)(xq);
    u16x4 xn1 = *(const u16x4*)(xq + 256);
    xp = xq;

    // poll partner flag, stage partner 1KB region into hW
    {
      int spin = 0;
      while (__hip_atomic_load(flagPar, __ATOMIC_RELAXED, __HIP_MEMORY_SCOPE_AGENT) < t + 1 &&
             spin < (1 << 18))
        spin++;
      const uint16_t* src = hx + ((size_t)((t + 1) & 1) * 128 + chunkPar) * 4096 +
                            (size_t)wave * 512 + (size_t)lane * 8;
      u32x4 v = load16_cc(src);
      asm volatile("s_waitcnt vmcnt(0)" ::: "memory");
      *(u32x4*)(hW + (size_t)regionPar * 512 + (size_t)lane * 8) = v;
    }

    xc0 = xn0; xc1 = xn1;
    __syncthreads();   // the ONE barrier: h(t+1) fully staged in hW
  }

  // final FC + sigmoid: h(80) in buffer 0 (NT even); s==0 blocks write
  if (s == 0) {
    const uint16_t* hB = hS + (NT & 1) * 8192;
#pragma unroll
    for (int rr = 0; rr < 2; rr++) {
      int row = wave * 2 + rr;
      // cols lane*8..+7: ks = lane>>2, logical qw = lane&3 -> swizzled slot
      int slot = (lane & 3) ^ ((row >> 1) & 3);
      const uint16_t* hr = hB + (size_t)(lane >> 2) * 512 + row * 32 + slot * 8;
      float p = 0.f;
#pragma unroll
      for (int j = 0; j < 8; j++) p += bf2f(hr[j]) * fcw[lane * 8 + j];
#pragma unroll
      for (int off = 32; off; off >>= 1) p += __shfl_down(p, off);
      if (lane == 0) {
        float logit = p + fcb[0];
        out[g * 16 + row] = 1.0f / (1.0f + __expf(-logit));
      }
    }
  }
}

// ---------------- launcher ----------------
extern "C" void kernel_launch(void* const* d_in, const int* in_sizes, int n_in,
                              void* d_out, int out_size, void* d_ws, size_t ws_size,
                              hipStream_t stream) {
  const int* tokens   = (const int*)d_in[0];
  const float* emb    = (const float*)d_in[1];
  const float* kernel_w = (const float*)d_in[2];
  const float* rec_w  = (const float*)d_in[3];
  const float* bias   = (const float*)d_in[4];
  const float* fcw    = (const float*)d_in[5];
  const float* fcb    = (const float*)d_in[6];
  float* out = (float*)d_out;

  // workspace: emb_bf16 51.2MB | kpack 0.5MB | rpack 0.5MB | xkp 83.9MB |
  //            hx 2MB | flags 16KB
  uint16_t* embb  = (uint16_t*)d_ws;
  uint16_t* kpack = embb + (size_t)NV * NE;
  uint16_t* rpack = kpack + (size_t)NE * NU;
  uint16_t* xkp   = rpack + (size_t)NU * NU;
  uint16_t* hx    = xkp + (size_t)NT * NB * NU;            // 1,048,576 u16
  int* flags      = (int*)(hx + (size_t)2 * 128 * 4096);
  // flags poisoned 0xAA -> 0xAAAAAAAA < 1 as signed int: valid initial state.

  hipLaunchKernelGGL(emb_to_bf16, dim3(25000), dim3(256), 0, stream, emb, embb);
  hipLaunchKernelGGL(pack_w, dim3(128), dim3(256), 0, stream, kernel_w, kpack);
  hipLaunchKernelGGL(pack_w, dim3(128), dim3(256), 0, stream, rec_w, rpack);
  hipLaunchKernelGGL(proj_gemm, dim3(1280), dim3(256), 0, stream, tokens, embb, kpack, bias, xkp);
  // 128 blocks: 64 row-groups x 2 column-halves. (Round-7 bug: this was 256.)
  hipLaunchKernelGGL(rnn_rec, dim3(128), dim3(512), 0, stream, xkp, rpack, fcw, fcb, hx, flags, out);
}